// Round 1
// baseline (527.689 us; speedup 1.0000x reference)
//
#include <hip/hip_runtime.h>

// ---------------------------------------------------------------------------
// LayerStacks (NNUE-style) on MI355X.
//   h0 = clamp01( x @ (w0[b]+w_fact)^T + b0[b] )   // 1024 -> 32, bf16 MFMA
//   h1 = clamp01( h0 @ w1[b]^T + b1[b] )           // 32 -> 32,  fp32 VALU
//   out = h1 @ w2[b]^T + b2[b]                     // 32 -> 1,   fp32 VALU
// Memory-bound: 256 MB of x read once. Rows bucket-sorted so each MFMA tile
// has a uniform bucket.
// ---------------------------------------------------------------------------

#define B_ROWS 65536
#define LK     1024       // 2*L1
#define TILE   128
#define NCHUNK 16         // K chunks of 64
#define MAIN_BLOCKS (B_ROWS / TILE + 8)   // 520: sum of per-bucket ceils <= this

// ws layout (bytes):
//   [0,256)        : int hdr[64]: counts[0..7], cursor[8..15], base[16..23], tcum[24..32]
//   [1024,132096)  : unsigned short sorted[65536]
//   [132096,...)   : wB: bf16 B-fragments of (w0+w_fact), 8 buckets * 16 chunks
//                    * 256 frags * 16 B = 512 KB
#define SORTED_OFF 1024
#define WB_OFF     (1024 + 131072)

typedef short  short8  __attribute__((ext_vector_type(8)));
typedef float  f32x16  __attribute__((ext_vector_type(16)));

__device__ __forceinline__ unsigned pkbf(float a, float b) {
    // round-to-nearest-even fp32 -> bf16, packed pair
    unsigned ua = __float_as_uint(a), ub = __float_as_uint(b);
    ua = (ua + 0x7FFFu + ((ua >> 16) & 1u)) >> 16;
    ub = (ub + 0x7FFFu + ((ub >> 16) & 1u)) >> 16;
    return (ua & 0xFFFFu) | (ub << 16);
}

// ls_indices may be int32 or int64 depending on harness dtype handling.
// If int64, the high words (odd int32 indices) of the first 64 elements are
// all zero (values are 0..7). Deterministic, identical in every block.
__device__ __forceinline__ bool detect_i64(const int* p) {
    int acc = 0;
#pragma unroll
    for (int i = 0; i < 64; ++i) acc |= p[2 * i + 1];
    return acc == 0;
}

__device__ __forceinline__ int load_bucket(const int* p, int r, bool i64) {
    return (i64 ? p[2 * r] : p[r]) & 7;
}

// --- K1: histogram -----------------------------------------------------------
__global__ void k_hist(const int* __restrict__ idx, int* __restrict__ hdr) {
    __shared__ int lc[8];
    int t = threadIdx.x;
    if (t < 8) lc[t] = 0;
    __syncthreads();
    bool i64 = detect_i64(idx);
    int r = blockIdx.x * 256 + t;
    int b = load_bucket(idx, r, i64);
    atomicAdd(&lc[b], 1);
    __syncthreads();
    if (t < 8) atomicAdd(&hdr[t], lc[t]);
}

// --- K2: prefix + tile plan --------------------------------------------------
__global__ void k_plan(int* __restrict__ hdr) {
    if (threadIdx.x == 0 && blockIdx.x == 0) {
        int base = 0, tt = 0;
        for (int b = 0; b < 8; ++b) {
            int c = hdr[b];
            hdr[16 + b] = base;   // segment base
            hdr[8 + b]  = base;   // scatter cursor
            hdr[24 + b] = tt;     // tile cumsum
            base += c;
            tt += (c + TILE - 1) / TILE;
        }
        hdr[24 + 8] = tt;         // total tiles
    }
}

// --- K3: scatter rows into bucket segments (wave-aggregated atomics) ---------
__global__ void k_scatter(const int* __restrict__ idx, int* __restrict__ hdr,
                          unsigned short* __restrict__ sorted) {
    bool i64 = detect_i64(idx);
    int t = threadIdx.x;
    int r = blockIdx.x * 256 + t;
    int b = load_bucket(idx, r, i64);
    int lane = t & 63;
#pragma unroll
    for (int bb = 0; bb < 8; ++bb) {
        unsigned long long m = __ballot(b == bb);
        if (m) {
            int leader = __ffsll((unsigned long long)m) - 1;
            int cnt = __popcll(m);
            int base = 0;
            if (lane == leader) base = atomicAdd(&hdr[8 + bb], cnt);
            base = __shfl(base, leader);
            if (b == bb) {
                int off = __popcll(m & ((1ull << lane) - 1ull));
                sorted[base + off] = (unsigned short)r;
            }
        }
    }
}

// --- K4: build bf16 B-fragments of (w0 + w_fact) -----------------------------
// frag f = ((bucket*16 + kc)*256 + (n + 32*khi)); holds W[bucket*32+n][kc*64+khi*8 .. +7]
__global__ void k_wprep(const float* __restrict__ w0, const float* __restrict__ wf,
                        uint4* __restrict__ wB) {
    int f = blockIdx.x * 256 + threadIdx.x;        // 32768 frags
    int b   = f >> 12;
    int kc  = (f >> 8) & 15;
    int idx = f & 255;
    int n   = idx & 31;
    int khi = idx >> 5;
    int k = kc * 64 + khi * 8;
    const float* p0 = w0 + (size_t)(b * 32 + n) * LK + k;
    const float* pf = wf + (size_t)n * LK + k;
    float v[8];
#pragma unroll
    for (int j = 0; j < 8; ++j) v[j] = p0[j] + pf[j];
    uint4 o;
    o.x = pkbf(v[0], v[1]); o.y = pkbf(v[2], v[3]);
    o.z = pkbf(v[4], v[5]); o.w = pkbf(v[6], v[7]);
    wB[f] = o;
}

// --- K5: main fused kernel ---------------------------------------------------
// Block = 256 threads = 4 waves; tile = 128 rows of one bucket; wave w owns
// rows [32w, 32w+32). LDS A/B staged in exact MFMA fragment order so every
// ds access is a lane-linear b128 (conflict-free).
__global__ __launch_bounds__(256) void k_main(
    const float* __restrict__ x, const unsigned short* __restrict__ sorted,
    const int* __restrict__ hdr, const uint4* __restrict__ wB,
    const float* __restrict__ b0, const float* __restrict__ w1,
    const float* __restrict__ b1, const float* __restrict__ w2,
    const float* __restrict__ b2, float* __restrict__ out)
{
    __shared__ __align__(16) unsigned char smem[45328];
    uint4* Abuf = (uint4*)smem;                 // [2][1024] uint4 = 32 KB
    uint4* Bbuf = (uint4*)(smem + 32768);       // [2][256]  uint4 =  8 KB
    float* w1s  = (float*)(smem + 40960);       // 1024 f
    float* b1s  = (float*)(smem + 45056);       // 32 f
    float* w2s  = (float*)(smem + 45184);       // 32 f
    float* b2s  = (float*)(smem + 45312);       // 1 f
    float* hbuf = (float*)smem;                 // aliases Abuf post-K-loop; 128*36*4 B

    int total = hdr[24 + 8];
    int g = blockIdx.x;
    if (g >= total) return;

    int bkt = 0;
    while (bkt < 7 && hdr[24 + bkt + 1] <= g) bkt++;
    int tile  = g - hdr[24 + bkt];
    int cnt   = hdr[bkt];
    int seg   = hdr[16 + bkt];
    int p0    = seg + tile * TILE;
    int nrows = min(TILE, cnt - tile * TILE);

    int t    = threadIdx.x;
    int lane = t & 63;
    int wv   = t >> 6;

    // stage small per-bucket params
    for (int q = t; q < 1024; q += 256) w1s[q] = w1[bkt * 1024 + q];
    if (t < 32) { b1s[t] = b1[bkt * 32 + t]; w2s[t] = w2[bkt * 32 + t]; }
    if (t == 0) b2s[0] = b2[bkt];

    // A staging mapping: thread t stages frag (row = (t&31)+32*it, khi = t>>5)
    // -> LDS uint4 index = 256*it + t (lane-linear).
    int khi = t >> 5;
    const float* xrow[4];
#pragma unroll
    for (int it = 0; it < 4; ++it) {
        int rloc = (t & 31) + 32 * it;
        int rc = min(rloc, nrows - 1);
        int gr = (int)sorted[p0 + rc];
        xrow[it] = x + (size_t)gr * LK + khi * 8;
    }
    const uint4* wBp = wB + (size_t)bkt * 4096 + t;

    float4 pfa[8];
    uint4  pfb;
    auto loadA = [&](int kc) {
#pragma unroll
        for (int it = 0; it < 4; ++it) {
            const float4* p = (const float4*)(xrow[it] + kc * 64);
            pfa[2 * it]     = p[0];
            pfa[2 * it + 1] = p[1];
        }
    };
    auto loadB = [&](int kc) { pfb = wBp[kc * 256]; };
    auto storeLDS = [&](int buf) {
#pragma unroll
        for (int it = 0; it < 4; ++it) {
            float4 a = pfa[2 * it], c = pfa[2 * it + 1];
            uint4 o;
            o.x = pkbf(a.x, a.y); o.y = pkbf(a.z, a.w);
            o.z = pkbf(c.x, c.y); o.w = pkbf(c.z, c.w);
            Abuf[buf * 1024 + 256 * it + t] = o;
        }
        Bbuf[buf * 256 + t] = pfb;
    };

    f32x16 acc;
#pragma unroll
    for (int i = 0; i < 16; ++i) acc[i] = 0.0f;

    // stage chunk 0
    loadA(0); loadB(0);
    storeLDS(0);
    __syncthreads();

    for (int kc = 0; kc < NCHUNK; ++kc) {
        int cur = kc & 1;
        if (kc < NCHUNK - 1) { loadA(kc + 1); loadB(kc + 1); }
        const short8* Af = (const short8*)&Abuf[cur * 1024 + 256 * wv];
        const short8* Bf = (const short8*)&Bbuf[cur * 256];
#pragma unroll
        for (int kk = 0; kk < 4; ++kk) {
            short8 av = Af[lane + 64 * kk];
            short8 bv = Bf[lane + 64 * kk];
            acc = __builtin_amdgcn_mfma_f32_32x32x16_bf16(av, bv, acc, 0, 0, 0);
        }
        if (kc < NCHUNK - 1) storeLDS(cur ^ 1);
        __syncthreads();
    }

    // epilogue: bias + clamp, h0 -> LDS (row stride 36 to dodge bank conflicts)
    int jl = lane & 31;
    float b0v = b0[bkt * 32 + jl];
#pragma unroll
    for (int reg = 0; reg < 16; ++reg) {
        int rowl = 32 * wv + (reg & 3) + 8 * (reg >> 2) + 4 * (lane >> 5);
        float h = acc[reg] + b0v;
        h = fminf(fmaxf(h, 0.0f), 1.0f);
        hbuf[rowl * 36 + jl] = h;
    }
    __syncthreads();

    // layers 1+2 in fp32: thread pair (2r, 2r+1) splits the 32 j2 outputs
    int r = t >> 1, half = t & 1;
    const float4* hr = (const float4*)&hbuf[r * 36];
    float4 ha[8];
#pragma unroll
    for (int q = 0; q < 8; ++q) ha[q] = hr[q];
    float partial = 0.0f;
#pragma unroll
    for (int jj = 0; jj < 16; ++jj) {
        int j2 = half * 16 + jj;
        const float4* wr = (const float4*)&w1s[j2 * 32];
        float s = b1s[j2];
#pragma unroll
        for (int q = 0; q < 8; ++q) {
            float4 w4 = wr[q];
            s += ha[q].x * w4.x + ha[q].y * w4.y + ha[q].z * w4.z + ha[q].w * w4.w;
        }
        s = fminf(fmaxf(s, 0.0f), 1.0f);
        partial += s * w2s[j2];
    }
    partial += __shfl_xor(partial, 1);
    if (half == 0 && r < nrows) {
        int gr = (int)sorted[p0 + r];
        out[gr] = partial + b2s[0];
    }
}

// ---------------------------------------------------------------------------
extern "C" void kernel_launch(void* const* d_in, const int* in_sizes, int n_in,
                              void* d_out, int out_size, void* d_ws, size_t ws_size,
                              hipStream_t stream) {
    const float* x   = (const float*)d_in[0];
    const int*   lsi = (const int*)  d_in[1];
    const float* wf  = (const float*)d_in[2];
    const float* w0  = (const float*)d_in[3];
    const float* b0  = (const float*)d_in[4];
    const float* w1  = (const float*)d_in[5];
    const float* b1  = (const float*)d_in[6];
    const float* w2  = (const float*)d_in[7];
    const float* b2  = (const float*)d_in[8];
    float* out = (float*)d_out;

    char* ws = (char*)d_ws;
    int* hdr = (int*)ws;
    unsigned short* sorted = (unsigned short*)(ws + SORTED_OFF);
    uint4* wB = (uint4*)(ws + WB_OFF);

    hipMemsetAsync(hdr, 0, 256, stream);
    k_hist   <<<B_ROWS / 256, 256, 0, stream>>>(lsi, hdr);
    k_plan   <<<1, 64, 0, stream>>>(hdr);
    k_scatter<<<B_ROWS / 256, 256, 0, stream>>>(lsi, hdr, sorted);
    k_wprep  <<<128, 256, 0, stream>>>(w0, wf, wB);
    k_main   <<<MAIN_BLOCKS, 256, 0, stream>>>(x, sorted, hdr, wB,
                                               b0, w1, b1, w2, b2, out);
}

// Round 2
// 486.367 us; speedup vs baseline: 1.0850x; 1.0850x over previous
//
#include <hip/hip_runtime.h>

// ---------------------------------------------------------------------------
// LayerStacks (NNUE-style) on MI355X.
//   h0 = clamp01( x @ (w0[b]+w_fact)^T + b0[b] )   // 1024 -> 32, bf16 MFMA
//   h1 = clamp01( h0 @ w1[b]^T + b1[b] )           // 32 -> 32,  fp32 VALU
//   out = h1 @ w2[b]^T + b2[b]                     // 32 -> 1,   fp32 VALU
// Memory-bound: 256 MB of x read once. Rows bucket-sorted so each MFMA tile
// has a uniform bucket.
// R1: single-block LDS sort (no global atomics), wprep fused into same launch,
//     2 launches total; k_main LDS 45.3->32 KB (B + epilogue params from L2),
//     4 blocks/CU.
// ---------------------------------------------------------------------------

#define B_ROWS 65536
#define LK     1024       // 2*L1
#define TILE   128
#define NCHUNK 16         // K chunks of 64
#define MAIN_BLOCKS (B_ROWS / TILE + 8)   // 520: sum of per-bucket ceils <= this

// ws layout (bytes):
//   [0,256)        : int hdr[64]: counts[0..7], segbase[16..23], tilecum[24..32]
//   [1024,132096)  : unsigned short sorted[65536]
//   [132096,...)   : wB: bf16 B-fragments of (w0+w_fact), 8 buckets * 16 chunks
//                    * 256 frags * 16 B = 512 KB
#define SORTED_OFF 1024
#define WB_OFF     (1024 + 131072)

typedef short  short8  __attribute__((ext_vector_type(8)));
typedef float  f32x16  __attribute__((ext_vector_type(16)));

__device__ __forceinline__ unsigned pkbf(float a, float b) {
    // round-to-nearest-even fp32 -> bf16, packed pair
    unsigned ua = __float_as_uint(a), ub = __float_as_uint(b);
    ua = (ua + 0x7FFFu + ((ua >> 16) & 1u)) >> 16;
    ub = (ub + 0x7FFFu + ((ub >> 16) & 1u)) >> 16;
    return (ua & 0xFFFFu) | (ub << 16);
}

// ls_indices may be int32 or int64. If int64, the high words (odd int32
// slots) of the first 64 elements are all zero (values 0..7). Deterministic.
__device__ __forceinline__ bool detect_i64(const int* p) {
    int acc = 0;
#pragma unroll
    for (int i = 0; i < 64; ++i) acc |= p[2 * i + 1];
    return acc == 0;
}

__device__ __forceinline__ int load_bucket(const int* p, int r, bool i64) {
    return (i64 ? p[2 * r] : p[r]) & 7;
}

// --- K1: fused prep ----------------------------------------------------------
// Block 0 (1024 thr = 16 waves): full bucket sort of 65536 rows, LDS-only.
// Blocks 1..32: build bf16 B-fragments of (w0+w_fact).
//   frag f = ((bucket*16+kc)*256 + (n + 32*khi)) holds W[b*32+n][kc*64+khi*8..+7]
__global__ __launch_bounds__(1024) void k_prep(
    const int* __restrict__ idx, const float* __restrict__ w0,
    const float* __restrict__ wf, uint4* __restrict__ wB,
    unsigned short* __restrict__ sorted, int* __restrict__ hdr)
{
    int t = threadIdx.x;

    if (blockIdx.x > 0) {
        // ---- weight prep ----
        int f = (blockIdx.x - 1) * 1024 + t;       // 32768 frags
        int b   = f >> 12;
        int kc  = (f >> 8) & 15;
        int i8  = f & 255;
        int n   = i8 & 31;
        int khi = i8 >> 5;
        int k = kc * 64 + khi * 8;
        const float* p0 = w0 + (size_t)(b * 32 + n) * LK + k;
        const float* pf = wf + (size_t)n * LK + k;
        float v[8];
#pragma unroll
        for (int j = 0; j < 8; ++j) v[j] = p0[j] + pf[j];
        uint4 o;
        o.x = pkbf(v[0], v[1]); o.y = pkbf(v[2], v[3]);
        o.z = pkbf(v[4], v[5]); o.w = pkbf(v[6], v[7]);
        wB[f] = o;
        return;
    }

    // ---- single-block sort ----
    __shared__ int wcnt[16][8];
    __shared__ int wbase[16][8];
    __shared__ int segb[8];

    bool i64 = detect_i64(idx);
    int wv = t >> 6, lane = t & 63;
    int rowbase = wv * 4096;            // 16 waves x 4096 rows = 65536

    // phase 1: per-wave counts via ballots (lane b accumulates bucket b)
    int mycnt = 0;
    for (int i = 0; i < 64; ++i) {
        int r = rowbase + i * 64 + lane;
        int b = load_bucket(idx, r, i64);
#pragma unroll
        for (int bb = 0; bb < 8; ++bb) {
            unsigned long long m = __ballot(b == bb);
            if (lane == bb) mycnt += __popcll(m);
        }
    }
    if (lane < 8) wcnt[wv][lane] = mycnt;
    __syncthreads();

    // phase 2: bucket totals, segment bases, tile plan (thread 0)
    if (t == 0) {
        int base = 0, tt = 0;
        for (int b = 0; b < 8; ++b) {
            int tot = 0;
            for (int w = 0; w < 16; ++w) tot += wcnt[w][b];
            hdr[b] = tot; hdr[16 + b] = base; hdr[24 + b] = tt;
            segb[b] = base;
            base += tot;
            tt += (tot + TILE - 1) / TILE;
        }
        hdr[24 + 8] = tt;
    }
    __syncthreads();

    // phase 3: per-(wave,bucket) exclusive base
    if (t < 128) {
        int w2 = t >> 3, b = t & 7;
        int base = segb[b];
        for (int w = 0; w < w2; ++w) base += wcnt[w][b];
        wbase[w2][b] = base;
    }
    __syncthreads();

    // phase 4: scatter; lane b<8 holds running cursor for bucket b
    int mycur = (lane < 8) ? wbase[wv][lane] : 0;
    for (int i = 0; i < 64; ++i) {
        int r = rowbase + i * 64 + lane;
        int b = load_bucket(idx, r, i64);
        unsigned long long mown = 0;
        int addc = 0;
#pragma unroll
        for (int bb = 0; bb < 8; ++bb) {
            unsigned long long m = __ballot(b == bb);
            if (b == bb) mown = m;
            if (lane == bb) addc = __popcll(m);
        }
        int base = __shfl(mycur, b);
        int rank = __popcll(mown & ((1ull << lane) - 1ull));
        sorted[base + rank] = (unsigned short)r;
        mycur += addc;
    }
}

// --- K2: main fused kernel ---------------------------------------------------
// Block = 256 threads = 4 waves; tile = 128 rows of one bucket; wave w owns
// rows [32w, 32w+32). A staged in LDS in exact MFMA fragment order
// (lane-linear b128, conflict-free); B-frags read straight from L2-resident
// wB table into registers each chunk.
__global__ __launch_bounds__(256, 4) void k_main(
    const float* __restrict__ x, const unsigned short* __restrict__ sorted,
    const int* __restrict__ hdr, const uint4* __restrict__ wB,
    const float* __restrict__ b0, const float* __restrict__ w1,
    const float* __restrict__ b1, const float* __restrict__ w2,
    const float* __restrict__ b2, float* __restrict__ out)
{
    __shared__ __align__(16) unsigned char smem[32768];
    uint4* Abuf = (uint4*)smem;                 // [2][1024] uint4 = 32 KB
    float* hbuf = (float*)smem;                 // aliases Abuf post-K-loop; 128*36*4 B

    int total = hdr[24 + 8];
    int g = blockIdx.x;
    if (g >= total) return;

    int bkt = 0;
    while (bkt < 7 && hdr[24 + bkt + 1] <= g) bkt++;
    int tile  = g - hdr[24 + bkt];
    int cnt   = hdr[bkt];
    int seg   = hdr[16 + bkt];
    int p0    = seg + tile * TILE;
    int nrows = min(TILE, cnt - tile * TILE);

    int t    = threadIdx.x;
    int lane = t & 63;
    int wv   = t >> 6;

    // A staging mapping: thread t stages frag (row = (t&31)+32*it, khi = t>>5)
    // -> LDS uint4 index = 256*it + t (lane-linear).
    int khi = t >> 5;
    const float* xrow[4];
#pragma unroll
    for (int it = 0; it < 4; ++it) {
        int rloc = (t & 31) + 32 * it;
        int rc = min(rloc, nrows - 1);
        int gr = (int)sorted[p0 + rc];
        xrow[it] = x + (size_t)gr * LK + khi * 8;
    }
    const short8* wBg = (const short8*)(wB + (size_t)bkt * 4096);

    float4 pfa[8];
    auto loadA = [&](int kc) {
#pragma unroll
        for (int it = 0; it < 4; ++it) {
            const float4* p = (const float4*)(xrow[it] + kc * 64);
            pfa[2 * it]     = p[0];
            pfa[2 * it + 1] = p[1];
        }
    };
    auto storeA = [&](int buf) {
#pragma unroll
        for (int it = 0; it < 4; ++it) {
            float4 a = pfa[2 * it], c = pfa[2 * it + 1];
            uint4 o;
            o.x = pkbf(a.x, a.y); o.y = pkbf(a.z, a.w);
            o.z = pkbf(c.x, c.y); o.w = pkbf(c.z, c.w);
            Abuf[buf * 1024 + 256 * it + t] = o;
        }
    };

    f32x16 acc;
#pragma unroll
    for (int i = 0; i < 16; ++i) acc[i] = 0.0f;

    loadA(0);
    storeA(0);
    __syncthreads();

    for (int kc = 0; kc < NCHUNK; ++kc) {
        int cur = kc & 1;
        // B frags for this chunk: L2-hit loads, issued first so their vmcnt
        // retires before the (later-issued) A prefetch loads.
        short8 bfr[4];
#pragma unroll
        for (int kk = 0; kk < 4; ++kk) bfr[kk] = wBg[kc * 256 + kk * 64 + lane];
        if (kc < NCHUNK - 1) loadA(kc + 1);
        const short8* Af = (const short8*)&Abuf[cur * 1024 + 256 * wv];
#pragma unroll
        for (int kk = 0; kk < 4; ++kk) {
            short8 av = Af[lane + 64 * kk];
            acc = __builtin_amdgcn_mfma_f32_32x32x16_bf16(av, bfr[kk], acc, 0, 0, 0);
        }
        if (kc < NCHUNK - 1) storeA(cur ^ 1);
        __syncthreads();
    }

    // epilogue: bias + clamp, h0 -> LDS (row stride 36 to dodge bank conflicts)
    int jl = lane & 31;
    float b0v = b0[bkt * 32 + jl];
#pragma unroll
    for (int reg = 0; reg < 16; ++reg) {
        int rowl = 32 * wv + (reg & 3) + 8 * (reg >> 2) + 4 * (lane >> 5);
        float h = acc[reg] + b0v;
        h = fminf(fmaxf(h, 0.0f), 1.0f);
        hbuf[rowl * 36 + jl] = h;
    }
    __syncthreads();

    // layers 1+2 in fp32: thread pair (2r, 2r+1) splits the 32 j2 outputs.
    // w1/b1/w2/b2 read straight from global (4 KB/bucket, L1/L2 broadcast).
    int r = t >> 1, half = t & 1;
    const float4* hr = (const float4*)&hbuf[r * 36];
    float4 ha[8];
#pragma unroll
    for (int q = 0; q < 8; ++q) ha[q] = hr[q];
    const float* w1b = w1 + (size_t)bkt * 1024;
    const float* b1b = b1 + bkt * 32;
    const float* w2b = w2 + bkt * 32;
    float partial = 0.0f;
#pragma unroll
    for (int jj = 0; jj < 16; ++jj) {
        int j2 = half * 16 + jj;
        const float4* wr = (const float4*)&w1b[j2 * 32];
        float s = b1b[j2];
#pragma unroll
        for (int q = 0; q < 8; ++q) {
            float4 w4 = wr[q];
            s += ha[q].x * w4.x + ha[q].y * w4.y + ha[q].z * w4.z + ha[q].w * w4.w;
        }
        s = fminf(fmaxf(s, 0.0f), 1.0f);
        partial += s * w2b[j2];
    }
    partial += __shfl_xor(partial, 1);
    if (half == 0 && r < nrows) {
        int gr = (int)sorted[p0 + r];
        out[gr] = partial + b2[bkt];
    }
}

// ---------------------------------------------------------------------------
extern "C" void kernel_launch(void* const* d_in, const int* in_sizes, int n_in,
                              void* d_out, int out_size, void* d_ws, size_t ws_size,
                              hipStream_t stream) {
    const float* x   = (const float*)d_in[0];
    const int*   lsi = (const int*)  d_in[1];
    const float* wf  = (const float*)d_in[2];
    const float* w0  = (const float*)d_in[3];
    const float* b0  = (const float*)d_in[4];
    const float* w1  = (const float*)d_in[5];
    const float* b1  = (const float*)d_in[6];
    const float* w2  = (const float*)d_in[7];
    const float* b2  = (const float*)d_in[8];
    float* out = (float*)d_out;

    char* ws = (char*)d_ws;
    int* hdr = (int*)ws;
    unsigned short* sorted = (unsigned short*)(ws + SORTED_OFF);
    uint4* wB = (uint4*)(ws + WB_OFF);

    k_prep<<<33, 1024, 0, stream>>>(lsi, w0, wf, wB, sorted, hdr);
    k_main<<<MAIN_BLOCKS, 256, 0, stream>>>(x, sorted, hdr, wB,
                                            b0, w1, b1, w2, b2, out);
}

// Round 3
// 434.347 us; speedup vs baseline: 1.2149x; 1.1198x over previous
//
#include <hip/hip_runtime.h>

// ---------------------------------------------------------------------------
// LayerStacks (NNUE-style) on MI355X.
//   h0 = clamp01( x @ (w0[b]+w_fact)^T + b0[b] )   // 1024 -> 32, bf16 MFMA
//   h1 = clamp01( h0 @ w1[b]^T + b1[b] )           // 32 -> 32,  fp32 VALU
//   out = h1 @ w2[b]^T + b2[b]                     // 32 -> 1,   fp32 VALU
// R2 finding: gathering 256-B granules from sorted (scattered ~32 KB apart)
// rows is DRAM page-activate bound (~830 GB/s). R3: tile = 32 sorted rows,
// FULL row (4 KB contiguous) per staging iteration; whole K=1024 in LDS as
// bf16; 4-way K-split across waves + LDS reduce.
// ---------------------------------------------------------------------------

#define B_ROWS 65536
#define LK     1024       // 2*L1
#define TILE   32
#define MAIN_BLOCKS (B_ROWS / TILE + 8)   // 2056 >= sum of per-bucket ceils
#define SROW   2056       // LDS row stride in bytes (1028 bf16): 2-way-free banks

// ws layout (bytes):
//   [0,256)        : int hdr[64]: counts[0..7], segbase[16..23], tilecum[24..32]
//   [1024,132096)  : unsigned short sorted[65536]
//   [132096,...)   : wB bf16 B-frags of (w0+w_fact): per bucket 4096 uint4;
//                    frag idx c*64+l holds W[bkt*32 + (l&31)][16c + 8*(l>>5) .. +8]
#define SORTED_OFF 1024
#define WB_OFF     (1024 + 131072)

typedef short  short8  __attribute__((ext_vector_type(8)));
typedef float  f32x16  __attribute__((ext_vector_type(16)));

__device__ __forceinline__ unsigned pkbf(float a, float b) {
    // round-to-nearest-even fp32 -> bf16, packed pair
    unsigned ua = __float_as_uint(a), ub = __float_as_uint(b);
    ua = (ua + 0x7FFFu + ((ua >> 16) & 1u)) >> 16;
    ub = (ub + 0x7FFFu + ((ub >> 16) & 1u)) >> 16;
    return (ua & 0xFFFFu) | (ub << 16);
}

// ls_indices may be int32 or int64. If int64, the high words (odd int32
// slots) of the first 64 elements are all zero (values 0..7). Deterministic.
__device__ __forceinline__ bool detect_i64(const int* p) {
    int acc = 0;
#pragma unroll
    for (int i = 0; i < 64; ++i) acc |= p[2 * i + 1];
    return acc == 0;
}

__device__ __forceinline__ int load_bucket(const int* p, int r, bool i64) {
    return (i64 ? p[2 * r] : p[r]) & 7;
}

// --- K1: fused prep ----------------------------------------------------------
// Block 0 (1024 thr = 16 waves): full bucket sort, one global pass over idx
// (buckets stashed in registers as nibbles), no global atomics.
// Blocks 1..32: build bf16 B-fragments of (w0+w_fact).
__global__ __launch_bounds__(1024) void k_prep(
    const int* __restrict__ idx, const float* __restrict__ w0,
    const float* __restrict__ wf, uint4* __restrict__ wB,
    unsigned short* __restrict__ sorted, int* __restrict__ hdr)
{
    int t = threadIdx.x;

    if (blockIdx.x > 0) {
        // ---- weight prep: 1 frag per thread ----
        int f = (blockIdx.x - 1) * 1024 + t;       // 32768 frags
        int b   = f >> 12;
        int i12 = f & 4095;
        int kc  = i12 >> 8;
        int i8  = i12 & 255;
        int n   = i8 & 31;
        int khi = i8 >> 5;
        int k = kc * 64 + khi * 8;
        const float* p0 = w0 + (size_t)(b * 32 + n) * LK + k;
        const float* pf = wf + (size_t)n * LK + k;
        float v[8];
#pragma unroll
        for (int j = 0; j < 8; ++j) v[j] = p0[j] + pf[j];
        uint4 o;
        o.x = pkbf(v[0], v[1]); o.y = pkbf(v[2], v[3]);
        o.z = pkbf(v[4], v[5]); o.w = pkbf(v[6], v[7]);
        wB[f] = o;
        return;
    }

    // ---- single-block sort ----
    __shared__ int wcnt[16][8];
    __shared__ int wbase[16][8];
    __shared__ int segb[8];

    bool i64 = detect_i64(idx);
    int wv = t >> 6, lane = t & 63;
    int rowbase = wv * 4096;            // 16 waves x 4096 rows

    // phase 1: one pass over idx; per-lane counts + nibble stash in regs
    unsigned nib[8] = {0, 0, 0, 0, 0, 0, 0, 0};
    int c[8] = {0, 0, 0, 0, 0, 0, 0, 0};
#pragma unroll 8
    for (int i = 0; i < 64; ++i) {
        int r = rowbase + i * 64 + lane;
        int b = load_bucket(idx, r, i64);
        nib[i >> 3] |= (unsigned)b << (4 * (i & 7));
#pragma unroll
        for (int bb = 0; bb < 8; ++bb) c[bb] += (b == bb) ? 1 : 0;
    }
#pragma unroll
    for (int bb = 0; bb < 8; ++bb) {
        int v = c[bb];
#pragma unroll
        for (int s = 1; s < 64; s <<= 1) v += __shfl_xor(v, s);
        if (lane == 0) wcnt[wv][bb] = v;
    }
    __syncthreads();

    // phase 2: totals, segment bases, tile plan
    if (t == 0) {
        int base = 0, tt = 0;
        for (int b = 0; b < 8; ++b) {
            int tot = 0;
            for (int w = 0; w < 16; ++w) tot += wcnt[w][b];
            hdr[b] = tot; hdr[16 + b] = base; hdr[24 + b] = tt;
            segb[b] = base;
            base += tot;
            tt += (tot + TILE - 1) / TILE;
        }
        hdr[24 + 8] = tt;
    }
    __syncthreads();

    // phase 3: per-(wave,bucket) exclusive base
    if (t < 128) {
        int w2 = t >> 3, b = t & 7;
        int base = segb[b];
        for (int w = 0; w < w2; ++w) base += wcnt[w][b];
        wbase[w2][b] = base;
    }
    __syncthreads();

    // phase 4: scatter from the register stash; lane b<8 holds bucket cursor
    int mycur = (lane < 8) ? wbase[wv][lane] : 0;
#pragma unroll
    for (int i = 0; i < 64; ++i) {
        int b = (nib[i >> 3] >> (4 * (i & 7))) & 7;
        unsigned long long mown = 0;
        int addc = 0;
#pragma unroll
        for (int bb = 0; bb < 8; ++bb) {
            unsigned long long m = __ballot(b == bb);
            if (b == bb) mown = m;
            if (lane == bb) addc = __popcll(m);
        }
        int base = __shfl(mycur, b);
        int rank = __popcll(mown & ((1ull << lane) - 1ull));
        sorted[base + rank] = (unsigned short)(rowbase + i * 64 + lane);
        mycur += addc;
    }
}

// --- K2: main fused kernel ---------------------------------------------------
// Block = 256 thr = 4 waves; tile = 32 sorted rows, full K=1024 in LDS (bf16,
// row-major, stride SROW). Staging iteration j reads ONE row = 4 KB fully
// contiguous. Waves K-split (wave w: K quarter [256w,256w+256) = 16 MFMAs),
// then LDS cross-wave reduce.
__global__ __launch_bounds__(256, 2) void k_main(
    const float* __restrict__ x, const unsigned short* __restrict__ sorted,
    const int* __restrict__ hdr, const uint4* __restrict__ wB,
    const float* __restrict__ b0, const float* __restrict__ w1,
    const float* __restrict__ b1, const float* __restrict__ w2,
    const float* __restrict__ b2, float* __restrict__ out)
{
    __shared__ __align__(16) unsigned char smem[TILE * SROW];  // 65792 B
    float* rbuf = (float*)smem;                    // reduce buf: 4*1024 f (alias)
    float* hb   = (float*)(smem + 16384);          // h0: 32 rows * 36 f (alias)

    int total = hdr[24 + 8];
    int g = blockIdx.x;
    if (g >= total) return;

    int bkt = 0;
    while (bkt < 7 && hdr[24 + bkt + 1] <= g) bkt++;
    int tile  = g - hdr[24 + bkt];
    int cnt   = hdr[bkt];
    int seg   = hdr[16 + bkt];
    int p0    = seg + tile * TILE;
    int nrows = min(TILE, cnt - tile * TILE);

    int t    = threadIdx.x;
    int lane = t & 63;
    int wv   = t >> 6;

    // ---- stage 32 rows; row j = 4 KB contiguous; thread t takes float4 #t ----
#pragma unroll
    for (int j0 = 0; j0 < 32; j0 += 8) {
        float4 v[8];
#pragma unroll
        for (int jj = 0; jj < 8; ++jj) {
            int j = j0 + jj;
            int gr = (int)sorted[p0 + min(j, nrows - 1)];
            v[jj] = ((const float4*)(x + (size_t)gr * LK))[t];
        }
#pragma unroll
        for (int jj = 0; jj < 8; ++jj) {
            int j = j0 + jj;
            uint2 o;
            o.x = pkbf(v[jj].x, v[jj].y);
            o.y = pkbf(v[jj].z, v[jj].w);
            *(uint2*)(smem + j * SROW + t * 8) = o;   // ds_write_b64, 2-way free
        }
    }
    __syncthreads();

    // ---- MFMA: wave wv does K range [wv*256, wv*256+256) = MFMAs c=16wv..+16
    const uint4* wBg = wB + (size_t)bkt * 4096;
    const unsigned char* Abase = smem + (size_t)(lane & 31) * SROW + 16 * (lane >> 5);

    f32x16 acc;
#pragma unroll
    for (int i = 0; i < 16; ++i) acc[i] = 0.0f;

    union UA { uint2 h[2]; short8 s; };
    union UB { uint4 u;    short8 s; };
#pragma unroll
    for (int cc = 0; cc < 16; ++cc) {
        int c = wv * 16 + cc;
        UA ua;
        ua.h[0] = *(const uint2*)(Abase + 32 * c);       // ds_read_b64 x2,
        ua.h[1] = *(const uint2*)(Abase + 32 * c + 8);   // 2-way aliasing = free
        UB ub;
        ub.u = wBg[c * 64 + lane];                       // L2-resident weights
        acc = __builtin_amdgcn_mfma_f32_32x32x16_bf16(ua.s, ub.s, acc, 0, 0, 0);
    }

    // ---- cross-wave K reduce via LDS ----
    __syncthreads();                                     // A reads done; safe to alias
#pragma unroll
    for (int r = 0; r < 16; ++r)
        rbuf[wv * 1024 + r * 64 + lane] = acc[r];        // lane-linear, free
    __syncthreads();

    // element e = r*64 + l of C: m = (r&3)+8*(r>>2)+4*(l>>5), n = l&31
#pragma unroll
    for (int q = 0; q < 4; ++q) {
        int e = t + 256 * q;
        float s = rbuf[e] + rbuf[1024 + e] + rbuf[2048 + e] + rbuf[3072 + e];
        int rr = e >> 6, ll = e & 63;
        int m = (rr & 3) + 8 * (rr >> 2) + 4 * (ll >> 5);
        int n = ll & 31;
        float h = s + b0[bkt * 32 + n];
        h = fminf(fmaxf(h, 0.0f), 1.0f);
        hb[m * 36 + n] = h;
    }
    __syncthreads();

    // ---- layers 1+2 (fp32), threads 0..63: pair (2r,2r+1) splits 32 outputs
    if (t < 64) {
        int r = t >> 1, half = t & 1;
        const float4* hr = (const float4*)(hb + r * 36);
        float4 ha[8];
#pragma unroll
        for (int q = 0; q < 8; ++q) ha[q] = hr[q];
        const float* w1b = w1 + (size_t)bkt * 1024;
        const float* b1b = b1 + bkt * 32;
        const float* w2b = w2 + bkt * 32;
        float partial = 0.0f;
#pragma unroll
        for (int jj = 0; jj < 16; ++jj) {
            int j2 = half * 16 + jj;
            const float4* wr = (const float4*)&w1b[j2 * 32];
            float s = b1b[j2];
#pragma unroll
            for (int q = 0; q < 8; ++q) {
                float4 w4 = wr[q];
                s += ha[q].x * w4.x + ha[q].y * w4.y + ha[q].z * w4.z + ha[q].w * w4.w;
            }
            s = fminf(fmaxf(s, 0.0f), 1.0f);
            partial += s * w2b[j2];
        }
        partial += __shfl_xor(partial, 1);
        if (half == 0 && r < nrows) {
            int gr = (int)sorted[p0 + r];
            out[gr] = partial + b2[bkt];
        }
    }
}

// ---------------------------------------------------------------------------
extern "C" void kernel_launch(void* const* d_in, const int* in_sizes, int n_in,
                              void* d_out, int out_size, void* d_ws, size_t ws_size,
                              hipStream_t stream) {
    const float* x   = (const float*)d_in[0];
    const int*   lsi = (const int*)  d_in[1];
    const float* wf  = (const float*)d_in[2];
    const float* w0  = (const float*)d_in[3];
    const float* b0  = (const float*)d_in[4];
    const float* w1  = (const float*)d_in[5];
    const float* b1  = (const float*)d_in[6];
    const float* w2  = (const float*)d_in[7];
    const float* b2  = (const float*)d_in[8];
    float* out = (float*)d_out;

    char* ws = (char*)d_ws;
    int* hdr = (int*)ws;
    unsigned short* sorted = (unsigned short*)(ws + SORTED_OFF);
    uint4* wB = (uint4*)(ws + WB_OFF);

    k_prep<<<33, 1024, 0, stream>>>(lsi, w0, wf, wB, sorted, hdr);
    k_main<<<MAIN_BLOCKS, 256, 0, stream>>>(x, sorted, hdr, wB,
                                            b0, w1, b1, w2, b2, out);
}